// Round 6
// baseline (278.215 us; speedup 1.0000x reference)
//
#include <hip/hip_runtime.h>
#include <cstdint>
#include <cstddef>

// ---------------- constants ----------------
__constant__ int LV_N[5]    = {49152, 12288, 3072, 768, 192};   // H*W*3
__constant__ int LV_K[5]    = {2000, 2000, 2000, 768, 192};     // min(PRE_NMS, N)
__constant__ int LV_OFF[5]  = {0, 2000, 4000, 6000, 6768};      // concat offsets
__constant__ int LV_UOFF[5] = {0, 49152, 61440, 64512, 65280};  // u-array offsets
__constant__ int LV_W[5]    = {128, 64, 32, 16, 8};
__constant__ int LV_S[5]    = {4, 8, 16, 32, 64};
__constant__ int LV_LOGHW[5]= {14, 12, 10, 8, 6};
// mask geometry (rows padded by 128 so the scan prefetch never needs bounds tests)
__constant__ int WPL[5]     = {32, 32, 32, 12, 3};              // words per row
__constant__ int MOFF[5]    = {0, 68096, 136192, 204288, 215040};
__constant__ int MB_BASE[6] = {0, 256, 512, 768, 804, 807};     // mask-block bases
__constant__ int MB_CT[5]   = {8, 8, 8, 3, 1};                  // col tiles per lvl
__constant__ int SGB6[6]    = {0, 12, 15, 16, 17, 18};          // 4096-elem tile bases

#define M_TOT 6960
#define U_PER_IMG 65472
#define MAX_OUT 1000
#define MWORDS_PER_IMG 216000
#define CAP 4096

struct Ptrs { const float* cls[5]; const float* reg[5]; };

// ---------------- XLA:CPU-compatible expf (Cephes/Eigen pexp, FMA-contracted) ----
__device__ __forceinline__ float xla_expf(float x) {
  const float exp_hi = 88.3762626647950f;
  const float exp_lo = -88.3762626647949f;
  const float log2ef = 1.44269504088896341f;
  const float c1 = 0.693359375f;
  const float c2 = -2.12194440e-4f;
  const float p0 = 1.9875691500e-4f;
  const float p1 = 1.3981999507e-3f;
  const float p2 = 8.3334519073e-3f;
  const float p3 = 4.1665795894e-2f;
  const float p4 = 1.6666665459e-1f;
  const float p5 = 5.0000001201e-1f;
  float xx = fminf(fmaxf(x, exp_lo), exp_hi);
  float fx = floorf(__fmaf_rn(xx, log2ef, 0.5f));
  float r = __fmaf_rn(fx, -c1, xx);
  r = __fmaf_rn(fx, -c2, r);
  float z = __fmul_rn(r, r);
  float y = __fmaf_rn(p0, r, p1);
  y = __fmaf_rn(y, r, p2);
  y = __fmaf_rn(y, r, p3);
  y = __fmaf_rn(y, r, p4);
  y = __fmaf_rn(y, r, p5);
  y = __fmaf_rn(y, z, r);
  y = __fadd_rn(y, 1.0f);
  int n = (int)fx;
  float two_n = __uint_as_float((unsigned)(n + 127) << 23);
  return __fmul_rn(y, two_n);
}

__device__ __forceinline__ float ref_sigmoid(float x) {
  return __fdiv_rn(1.0f, __fadd_rn(1.0f, xla_expf(-x)));
}

// ================= K0: wide sigmoid + 4096-bin score-bit histogram ============
__global__ __launch_bounds__(1024) void k_sig(Ptrs p, unsigned* u_arr,
                                              unsigned* ghist) {
  const int img = blockIdx.y;
  const int bx = blockIdx.x;
  int lvl = 0;
  while (bx >= SGB6[lvl + 1]) ++lvl;
  const int N = LV_N[lvl], LOGHW = LV_LOGHW[lvl];
  const int HW = 1 << LOGHW;
  const int e0 = (bx - SGB6[lvl]) * 4096;
  const int e1 = (e0 + 4096 < N) ? e0 + 4096 : N;
  const int tid = (int)threadIdx.x;
  __shared__ unsigned h[4096];
  for (int e = tid; e < 4096; e += 1024) h[e] = 0;
  __syncthreads();
  const float* cls = p.cls[lvl] + (size_t)img * N;
  unsigned* u = u_arr + img * U_PER_IMG + LV_UOFF[lvl];
  for (int e = e0 + tid; e < e1; e += 1024) {
    float logit = cls[e];                  // plane-major: fully coalesced
    unsigned ub = __float_as_uint(ref_sigmoid(logit));
    int a = e >> LOGHW, pix = e & (HW - 1);
    u[pix * 3 + a] = ub;                   // channel-last (reference order)
    atomicAdd(&h[(ub >> 18) & 4095u], 1u);
  }
  __syncthreads();
  unsigned* gh = ghist + (size_t)(img * 5 + lvl) * 4096;
  for (int e = tid; e < 4096; e += 1024)
    if (h[e]) atomicAdd(&gh[e], h[e]);
}

// ================= K1a: threshold pick (O(bins), N-scan only on fallback) =====
__global__ __launch_bounds__(1024) void k_thresh(const unsigned* u_arr,
    const unsigned* ghist, unsigned long long* T64_arr) {
  const int blk = blockIdx.x;
  const int img = blk / 5, lvl = blk % 5;
  const int N = LV_N[lvl], K = LV_K[lvl];
  const int tid = (int)threadIdx.x;
  if (N <= K) { if (tid == 0) T64_arr[blk] = 0ULL; return; }
  __shared__ unsigned h[4096], sA[4096], sB[4096];
  __shared__ unsigned sh_D, sh_sD, sh_sD1;
  const unsigned* u = u_arr + img * U_PER_IMG + LV_UOFF[lvl];

  for (int e = tid; e < 4096; e += 1024)
    h[e] = ghist[(size_t)blk * 4096 + e];
  __syncthreads();

  unsigned long long prefix = 0;
  unsigned want = (unsigned)K, above = 0;
  const int shifts[6] = {50, 38, 26, 14, 2, 0};
  const int widths[6] = {12, 12, 12, 12, 12, 2};
  for (int rd = 0; rd < 6; ++rd) {
    const int shift = shifts[rd], width = widths[rd];
    const int nb = 1 << width;
    if (rd > 0) {                          // fallback: exact rescan (rare)
      for (int e = tid; e < nb; e += 1024) h[e] = 0;
      __syncthreads();
      for (int i = tid; i < N; i += 1024) {
        unsigned long long key =
            ((unsigned long long)u[i] << 32) | (unsigned)(~(unsigned)i);
        if ((key >> (shift + width)) == prefix)
          atomicAdd(&h[(unsigned)(key >> shift) & (unsigned)(nb - 1)], 1u);
      }
      __syncthreads();
    }
    // suffix scan s[d] = sum_{v>=d} h[v]
    unsigned *Ap = sA, *Bp = sB;
    for (int e = tid; e < nb; e += 1024) Ap[e] = h[e];
    __syncthreads();
    for (int off = 1; off < nb; off <<= 1) {
      for (int e = tid; e < nb; e += 1024)
        Bp[e] = Ap[e] + ((e + off < nb) ? Ap[e + off] : 0u);
      __syncthreads();
      unsigned* t = Ap; Ap = Bp; Bp = t;
    }
    for (int e = tid; e < nb; e += 1024) {
      unsigned s = Ap[e], sn = (e + 1 < nb) ? Ap[e + 1] : 0u;
      if (s >= want && sn < want) { sh_D = (unsigned)e; sh_sD = s; sh_sD1 = sn; }
    }
    __syncthreads();
    unsigned D = sh_D, sD = sh_sD, sD1 = sh_sD1;
    unsigned long long npref = (prefix << width) | (unsigned long long)D;
    if (above + sD <= (unsigned)CAP || rd == 5) {
      if (tid == 0) T64_arr[blk] = npref << shift;
      return;                              // uniform decision across block
    }
    above += sD1; want -= sD1; prefix = npref;
    __syncthreads();
  }
}

// ================= K1b: wide collect of keys >= T64 (unordered) ==============
__global__ __launch_bounds__(1024) void k_collect(const unsigned* u_arr,
    const unsigned long long* T64_arr, unsigned long long* gtk, unsigned* gcnt) {
  const int img = blockIdx.y;
  const int bx = blockIdx.x;
  int lvl = 0;
  while (bx >= SGB6[lvl + 1]) ++lvl;
  const int N = LV_N[lvl];
  const int e0 = (bx - SGB6[lvl]) * 4096;
  const int e1 = (e0 + 4096 < N) ? e0 + 4096 : N;
  const int tid = (int)threadIdx.x;
  const int lane = tid & 63;
  const unsigned long long T = T64_arr[img * 5 + lvl];
  const unsigned* u = u_arr + img * U_PER_IMG + LV_UOFF[lvl];
  unsigned long long* dst = gtk + (size_t)(img * 5 + lvl) * CAP;
  unsigned* cnt = gcnt + (img * 5 + lvl);
  for (int e = e0 + tid; e < e1; e += 1024) {
    unsigned long long key =
        ((unsigned long long)u[e] << 32) | (unsigned)(~(unsigned)e);
    bool pred = key >= T;
    unsigned long long bm = __ballot(pred);
    if (bm) {
      int leader = __ffsll((long long)bm) - 1;
      unsigned sbase = 0;
      if (lane == leader) sbase = atomicAdd(cnt, (unsigned)__popcll(bm));
      sbase = __shfl(sbase, leader);
      if (pred) {
        unsigned slot = sbase + (unsigned)__popcll(bm & ((1ULL << lane) - 1ULL));
        if (slot < (unsigned)CAP) dst[slot] = key;
      }
    }
  }
}

// ================= K1c: sort P (adaptive) + decode + partition ================
__global__ __launch_bounds__(1024) void k_sort(Ptrs p,
    const unsigned long long* gtk, const unsigned* gcnt,
    float* cand_box, float* cand_s,
    float* n_x1, float* n_y1, float* n_x2, float* n_y2, float* n_ar,
    float* n_sc, unsigned* n_pos, unsigned* V_arr) {
  const int blk = blockIdx.x;
  const int img = blk / 5, lvl = blk % 5;
  const int N = LV_N[lvl], K = LV_K[lvl], W = LV_W[lvl], S = LV_S[lvl];
  const int HW = N / 3;
  const float* reg = p.reg[lvl] + (size_t)img * 12 * HW;
  const int tid = (int)threadIdx.x;

  __shared__ unsigned long long tk[CAP];
  __shared__ unsigned scanA[2048];
  __shared__ unsigned scanB[2048];

  unsigned cnt = gcnt[img * 5 + lvl];
  if (cnt > (unsigned)CAP) cnt = CAP;
  int P = 256;
  while (P < (int)cnt) P <<= 1;            // cnt >= K always, so P >= K
  const unsigned long long* src = gtk + (size_t)(img * 5 + lvl) * CAP;
  for (int e = tid; e < P; e += 1024)
    tk[e] = (e < (int)cnt) ? ~src[e] : ~0ULL;   // flipped -> ascending = score desc

  // bitonic sort P
  for (int size = 2; size < P; size <<= 1) {
    for (int stride = size >> 1; stride > 0; stride >>= 1) {
      __syncthreads();
      for (int q = tid; q < (P >> 1); q += 1024) {
        int pos = 2 * q - (q & (stride - 1));
        bool ddd = ((q & (size >> 1)) == 0);
        unsigned long long A = tk[pos], B = tk[pos + stride];
        if ((A > B) == ddd) { tk[pos] = B; tk[pos + stride] = A; }
      }
    }
  }
  for (int stride = P >> 1; stride > 0; stride >>= 1) {
    __syncthreads();
    for (int q = tid; q < (P >> 1); q += 1024) {
      int pos = 2 * q - (q & (stride - 1));
      unsigned long long A = tk[pos], B = tk[pos + stride];
      if (A > B) { tk[pos] = B; tk[pos + stride] = A; }
    }
  }
  __syncthreads();

  // decode per rank, keep boxes in registers (2 ranks/thread)
  for (int r = tid; r < 2048; r += 1024) scanA[r] = 0u;
  const int KK = K;
  const float MRf = 4.135166556742356f;  // |log(16/1000)| rounded to f32
  float bx1[2], by1[2], bx2[2], by2[2], bsc[2];
  #pragma unroll
  for (int slot = 0; slot < 2; ++slot) {
    int r = tid + slot * 1024;
    if (r >= KK) continue;
    unsigned long long key = ~tk[r];
    unsigned ubits = (unsigned)(key >> 32);
    unsigned idx = ~((unsigned)key);
    int a = (int)(idx % 3u); int pix = (int)(idx / 3u);
    int xq = pix % W, yq = pix / W;
    float dx = reg[(a * 4 + 0) * HW + pix];
    float dy = reg[(a * 4 + 1) * HW + pix];
    float dw = reg[(a * 4 + 2) * HW + pix];
    float dh = reg[(a * 4 + 3) * HW + pix];
    double rr = (a == 0) ? 0.5 : (a == 1 ? 1.0 : 2.0);
    double hr = sqrt(rr), wr = 1.0 / hr;
    double st = (double)S;
    double wsd = st * wr * 8.0, hsd = st * hr * 8.0;
    double sxd = (double)(xq * S), syd = (double)(yq * S);
    float a0 = (float)(sxd - 0.5 * wsd), a1 = (float)(syd - 0.5 * hsd);
    float a2 = (float)(sxd + 0.5 * wsd), a3 = (float)(syd + 0.5 * hsd);
    float px = __fmul_rn(__fadd_rn(a0, a2), 0.5f);
    float py = __fmul_rn(__fadd_rn(a1, a3), 0.5f);
    float pw = __fsub_rn(a2, a0), ph = __fsub_rn(a3, a1);
    float dwc = fminf(fmaxf(dw, -MRf), MRf);
    float dhc = fminf(fmaxf(dh, -MRf), MRf);
    float gw = __fmul_rn(pw, xla_expf(dwc));
    float gh = __fmul_rn(ph, xla_expf(dhc));
    float gx = __fmaf_rn(pw, dx, px);
    float gy = __fmaf_rn(ph, dy, py);
    float x1 = fminf(fmaxf(__fmaf_rn(gw, -0.5f, gx), 0.0f), 512.0f);
    float y1 = fminf(fmaxf(__fmaf_rn(gh, -0.5f, gy), 0.0f), 512.0f);
    float x2 = fminf(fmaxf(__fmaf_rn(gw,  0.5f, gx), 0.0f), 512.0f);
    float y2 = fminf(fmaxf(__fmaf_rn(gh,  0.5f, gy), 0.0f), 512.0f);
    bool valid = (__fsub_rn(x2, x1) > 0.0f) && (__fsub_rn(y2, y1) > 0.0f);
    int pos = img * M_TOT + LV_OFF[lvl] + r;
    cand_box[(size_t)pos * 4 + 0] = x1;
    cand_box[(size_t)pos * 4 + 1] = y1;
    cand_box[(size_t)pos * 4 + 2] = x2;
    cand_box[(size_t)pos * 4 + 3] = y2;
    float score = __uint_as_float(ubits);
    float sc = valid ? score : -1.0f;
    cand_s[pos] = sc;
    scanA[r] = valid ? 1u : 0u;
    bx1[slot] = x1; by1[slot] = y1; bx2[slot] = x2; by2[slot] = y2;
    bsc[slot] = sc;
  }
  __syncthreads();

  // stable partition (valids first) via inclusive scan over 2048
  unsigned* Ap = scanA; unsigned* Bp = scanB;
  for (int off = 1; off < 2048; off <<= 1) {
    for (int r2 = tid; r2 < 2048; r2 += 1024)
      Bp[r2] = Ap[r2] + ((r2 >= off) ? Ap[r2 - off] : 0u);
    __syncthreads();
    unsigned* t = Ap; Ap = Bp; Bp = t;
  }
  unsigned V = (KK > 0) ? Ap[KK - 1] : 0u;
  const float offv = __fmul_rn((float)lvl, 513.0f);
  #pragma unroll
  for (int slot = 0; slot < 2; ++slot) {
    int r = tid + slot * 1024;
    if (r >= KK) continue;
    unsigned incl = Ap[r];
    unsigned fl = incl - ((r > 0) ? Ap[r - 1] : 0u);
    unsigned excl = incl - fl;
    unsigned pdst = fl ? excl : V + ((unsigned)r - excl);
    int dst = img * M_TOT + LV_OFF[lvl] + (int)pdst;
    float ox1 = __fadd_rn(bx1[slot], offv), oy1 = __fadd_rn(by1[slot], offv);
    float ox2 = __fadd_rn(bx2[slot], offv), oy2 = __fadd_rn(by2[slot], offv);
    n_x1[dst] = ox1; n_y1[dst] = oy1; n_x2[dst] = ox2; n_y2[dst] = oy2;
    n_ar[dst] = __fmul_rn(__fsub_rn(ox2, ox1), __fsub_rn(oy2, oy1));
    n_sc[dst] = bsc[slot];
    n_pos[dst] = (unsigned)(LV_OFF[lvl] + r);
  }
  if (tid == 0) V_arr[img * 5 + lvl] = V;
}

// ================= K2a: suppression bit-matrix build =========================
__global__ __launch_bounds__(256) void k_mask(
    const float* n_x1, const float* n_y1, const float* n_x2, const float* n_y2,
    const float* n_ar, unsigned long long* mask) {
  const int img = blockIdx.y;
  const int bx = blockIdx.x;
  int lvl = 0;
  while (bx >= MB_BASE[lvl + 1]) ++lvl;
  const int t = bx - MB_BASE[lvl];
  const int ct = MB_CT[lvl];
  const int rt = t / ct, c = t % ct;
  const int K = LV_K[lvl];
  const int row0 = rt * 64, col0 = c * 256;
  if (col0 + 255 <= row0) return;  // entire tile has j <= r: bits never consumed

  __shared__ float4 cb4[256];
  __shared__ float cba[256];
  __shared__ float4 rb4[64];
  __shared__ float rba[64];
  const int base = img * M_TOT + LV_OFF[lvl];
  const int tid = (int)threadIdx.x;
  if (tid < 64) {
    int r = row0 + tid;
    if (r < K) {
      rb4[tid] = make_float4(n_x1[base + r], n_y1[base + r],
                             n_x2[base + r], n_y2[base + r]);
      rba[tid] = n_ar[base + r];
    }
  }
  {
    int j = col0 + tid;
    if (j < K) {
      cb4[tid] = make_float4(n_x1[base + j], n_y1[base + j],
                             n_x2[base + j], n_y2[base + j]);
      cba[tid] = n_ar[base + j];
    }
  }
  __syncthreads();
  const int wl = tid >> 6, rl = tid & 63;
  const int r = row0 + rl;
  if (r >= K) return;
  const float4 rb = rb4[rl];
  const float rar = rba[rl];
  unsigned long long word = 0ULL;
  const int jbase = wl * 64;
  const int jmax = K - col0 - jbase;   // bit k valid iff k < jmax
  #pragma unroll 16
  for (int k = 0; k < 64; ++k) {
    float4 cb = cb4[jbase + k];        // broadcast: all lanes same address
    float car = cba[jbase + k];
    float iw = fmaxf(__fsub_rn(fminf(rb.z, cb.z), fmaxf(rb.x, cb.x)), 0.0f);
    float ih = fmaxf(__fsub_rn(fminf(rb.w, cb.w), fmaxf(rb.y, cb.y)), 0.0f);
    float inter = __fmul_rn(iw, ih);
    float uni = __fsub_rn(__fadd_rn(rar, car), inter);
    float iou = (uni > 0.0f) ? __fdiv_rn(inter, uni) : 0.0f;
    if (iou > 0.7f && k < jmax) word |= (1ULL << k);
  }
  mask[(size_t)img * MWORDS_PER_IMG + MOFF[lvl] +
       (size_t)r * WPL[lvl] + (size_t)((col0 >> 6) + wl)] = word;
}

// ================= K2b: serial greedy scan over bit-matrix ====================
// Lane-local replicated chunk word (cw): keep-test is a register bit-extract,
// no cross-lane op on the chain (ONE shfl per 64 rows). All suppression work
// sits inside a rarely-taken branch. Two prefetch rings (rows depth 32 + diag
// depth 16) = 63 outstanding loads; mask rows padded 128 -> no bounds checks.
__global__ __launch_bounds__(64) void k_scan(const unsigned long long* mask,
    const unsigned* n_pos, const float* n_sc, const unsigned* V_arr,
    unsigned* kept_pos, unsigned long long* kept_key, unsigned* kept_cnt) {
  const int blk = blockIdx.x;
  const int img = blk / 5, lvl = blk % 5;
  const int K = LV_K[lvl], wpl = WPL[lvl];
  const int lane = (int)threadIdx.x;
  const unsigned long long* mb =
      mask + (size_t)img * MWORDS_PER_IMG + MOFF[lvl];
  const int ln = lane < wpl ? lane : 0;  // clamped word index (dup loads ok)

  __shared__ unsigned skept[MAX_OUT + 64];

  const int V = (int)V_arr[img * 5 + lvl];
  unsigned long long alive = 0ULL;
  if (lane < wpl) {
    int lo = lane * 64, hi = V < lo + 64 ? V : lo + 64;
    if (hi > lo) alive = (hi - lo == 64) ? ~0ULL : ((1ULL << (hi - lo)) - 1ULL);
  }

  unsigned long long rowb[32];
  unsigned long long diagb[16];
  #pragma unroll
  for (int d = 0; d < 32; ++d) rowb[d] = mb[(size_t)d * wpl + ln];
  #pragma unroll
  for (int d = 0; d < 16; ++d) diagb[d] = mb[(size_t)d * wpl];  // rows 0..15, col word 0

  int kept = 0;
  for (int r0 = 0; r0 < K; r0 += 64) {
    unsigned long long cw = __shfl(alive, r0 >> 6);
    unsigned cwlo = (unsigned)cw, cwhi = (unsigned)(cw >> 32);

    // ---- sub-block A: rows r0 .. r0+31 ----
    if (cwlo) {
      #pragma unroll
      for (int d = 0; d < 32; ++d) {
        if ((cwlo >> d) & 1u) {
          unsigned long long dg = diagb[d & 15];
          cwlo &= ~(unsigned)dg;
          cwhi &= ~(unsigned)(dg >> 32);
          alive &= ~rowb[d];
          if (lane == 0) skept[kept] = (unsigned)(r0 + d);
          ++kept;
        }
        { int rp = r0 + d + 16; diagb[d & 15] = mb[(size_t)rp * wpl + (rp >> 6)]; }
        { int rr = r0 + d + 32; rowb[d] = mb[(size_t)rr * wpl + ln]; }
      }
    } else {
      #pragma unroll
      for (int d = 0; d < 32; ++d) {
        { int rp = r0 + d + 16; diagb[d & 15] = mb[(size_t)rp * wpl + (rp >> 6)]; }
        { int rr = r0 + d + 32; rowb[d] = mb[(size_t)rr * wpl + ln]; }
      }
    }

    // ---- sub-block B: rows r0+32 .. r0+63 ----
    if (cwhi) {
      #pragma unroll
      for (int d = 0; d < 32; ++d) {
        if ((cwhi >> d) & 1u) {
          unsigned long long dg = diagb[d & 15];
          cwhi &= ~(unsigned)(dg >> 32);       // low half already passed
          alive &= ~rowb[d];
          if (lane == 0) skept[kept] = (unsigned)(r0 + 32 + d);
          ++kept;
        }
        { int rp = r0 + d + 48; diagb[d & 15] = mb[(size_t)rp * wpl + (rp >> 6)]; }
        { int rr = r0 + d + 64; rowb[d] = mb[(size_t)rr * wpl + ln]; }
      }
    } else {
      #pragma unroll
      for (int d = 0; d < 32; ++d) {
        { int rp = r0 + d + 48; diagb[d & 15] = mb[(size_t)rp * wpl + (rp >> 6)]; }
        { int rr = r0 + d + 64; rowb[d] = mb[(size_t)rr * wpl + ln]; }
      }
    }

    if (kept >= MAX_OUT) break;   // overshoot <=64 buffered; truncated below
  }
  if (kept > MAX_OUT) kept = MAX_OUT;
  __syncthreads();
  const int base = img * M_TOT + LV_OFF[lvl];
  const size_t bo = (size_t)(img * 5 + lvl) * 1024;
  for (int i = lane; i < kept; i += 64) {
    unsigned r = skept[i];
    unsigned pp = n_pos[base + (int)r];
    kept_pos[bo + i] = pp;
    kept_key[bo + i] =
        ((unsigned long long)__float_as_uint(n_sc[base + (int)r]) << 32) |
        (unsigned)(~pp);
  }
  if (lane == 0) kept_cnt[img * 5 + lvl] = (unsigned)kept;
}

// ================= K3: per-image merge of kept lists -> output rows ===========
__global__ __launch_bounds__(1024) void k_merge(const float* cand_box,
    const float* cand_s, const unsigned* kept_pos,
    const unsigned long long* kept_key, const unsigned* kept_cnt, float* out) {
  const int img = blockIdx.x;
  const int tid = (int)threadIdx.x;
  __shared__ unsigned cnts[5];
  __shared__ unsigned long long skey[5][1024];
  if (tid < 5) {
    unsigned c = kept_cnt[img * 5 + tid];
    cnts[tid] = c < (unsigned)MAX_OUT ? c : (unsigned)MAX_OUT;
  }
  __syncthreads();
  for (int e = tid; e < 5 * 1024; e += 1024) {
    int l = e >> 10, s = e & 1023;
    skey[l][s] = (s < (int)cnts[l])
        ? kept_key[(size_t)(img * 5 + l) * 1024 + s] : 0ULL;
  }
  __syncthreads();
  unsigned T = cnts[0] + cnts[1] + cnts[2] + cnts[3] + cnts[4];
  unsigned Tc = T < (unsigned)MAX_OUT ? T : (unsigned)MAX_OUT;
  for (int r = (int)Tc + tid; r < MAX_OUT; r += 1024) {
    float* o = out + (size_t)img * (MAX_OUT * 5) + (size_t)r * 5;
    o[0] = 0.f; o[1] = 0.f; o[2] = 0.f; o[3] = 0.f; o[4] = 0.f;
  }
  for (int e = tid; e < 5 * 1024; e += 1024) {
    int l = e >> 10, s = e & 1023;
    if (s >= (int)cnts[l]) continue;
    unsigned long long k0 = skey[l][s];
    unsigned rank = (unsigned)s;
    #pragma unroll
    for (int l2 = 0; l2 < 5; ++l2) {
      if (l2 == l) continue;
      int lo = 0, hi = (int)cnts[l2];
      while (lo < hi) {
        int mid = (lo + hi) >> 1;
        if (skey[l2][mid] > k0) lo = mid + 1; else hi = mid;
      }
      rank += (unsigned)lo;
    }
    if (rank < (unsigned)MAX_OUT) {
      unsigned pos = kept_pos[(size_t)(img * 5 + l) * 1024 + s];
      const float* b = cand_box + (size_t)(img * M_TOT + pos) * 4;
      float* o = out + (size_t)img * (MAX_OUT * 5) + (size_t)rank * 5;
      o[0] = b[0]; o[1] = b[1]; o[2] = b[2]; o[3] = b[3];
      o[4] = cand_s[img * M_TOT + pos];
    }
  }
}

// ================= host launch =================
extern "C" void kernel_launch(void* const* d_in, const int* in_sizes, int n_in,
                              void* d_out, int out_size, void* d_ws, size_t ws_size,
                              hipStream_t stream) {
  Ptrs p;
  bool interleaved = (n_in == 10 && in_sizes[1] == 4 * 12 * 128 * 128);
  for (int l = 0; l < 5; ++l) {
    if (interleaved) {
      p.cls[l] = (const float*)d_in[2 * l];
      p.reg[l] = (const float*)d_in[2 * l + 1];
    } else {
      p.cls[l] = (const float*)d_in[l];
      p.reg[l] = (const float*)d_in[5 + l];
    }
  }
  uint8_t* w = (uint8_t*)d_ws;
  size_t o = 0;
  auto carve = [&](size_t bytes) {
    void* ptr = w + o;
    o += (bytes + 255) & ~(size_t)255;
    return ptr;
  };
  // gcnt + ghist adjacent -> one memset zeroes both
  unsigned* gcnt = (unsigned*)carve((size_t)20 * 4);                 // 256B slot
  unsigned* ghist = (unsigned*)carve((size_t)20 * 4096 * 4);
  size_t zero_bytes = 256 + (size_t)20 * 4096 * 4;
  unsigned long long* T64_arr = (unsigned long long*)carve((size_t)20 * 8);
  unsigned* u_arr = (unsigned*)carve((size_t)4 * U_PER_IMG * 4);
  float* cand_box = (float*)carve((size_t)4 * M_TOT * 4 * 4);
  float* cand_s = (float*)carve((size_t)4 * M_TOT * 4);
  float* n_x1 = (float*)carve((size_t)4 * M_TOT * 4);
  float* n_y1 = (float*)carve((size_t)4 * M_TOT * 4);
  float* n_x2 = (float*)carve((size_t)4 * M_TOT * 4);
  float* n_y2 = (float*)carve((size_t)4 * M_TOT * 4);
  float* n_ar = (float*)carve((size_t)4 * M_TOT * 4);
  float* n_sc = (float*)carve((size_t)4 * M_TOT * 4);
  unsigned* n_pos = (unsigned*)carve((size_t)4 * M_TOT * 4);
  unsigned* V_arr = (unsigned*)carve((size_t)20 * 4);
  unsigned* kept_pos = (unsigned*)carve((size_t)4 * 5 * 1024 * 4);
  unsigned long long* kept_key = (unsigned long long*)carve((size_t)4 * 5 * 1024 * 8);
  unsigned* kept_cnt = (unsigned*)carve((size_t)20 * 4);
  unsigned long long* mask = (unsigned long long*)carve((size_t)4 * MWORDS_PER_IMG * 8);
  // gtk (20*4096 u64 = 640KB) aliases mask: dead before k_mask writes it.
  unsigned long long* gtk = mask;
  (void)ws_size; (void)out_size;

  hipMemsetAsync(gcnt, 0, zero_bytes, stream);
  k_sig<<<dim3(18, 4), 1024, 0, stream>>>(p, u_arr, ghist);
  k_thresh<<<20, 1024, 0, stream>>>(u_arr, ghist, T64_arr);
  k_collect<<<dim3(18, 4), 1024, 0, stream>>>(u_arr, T64_arr, gtk, gcnt);
  k_sort<<<20, 1024, 0, stream>>>(p, gtk, gcnt, cand_box, cand_s,
      n_x1, n_y1, n_x2, n_y2, n_ar, n_sc, n_pos, V_arr);
  k_mask<<<dim3(807, 4), 256, 0, stream>>>(n_x1, n_y1, n_x2, n_y2, n_ar, mask);
  k_scan<<<20, 64, 0, stream>>>(mask, n_pos, n_sc, V_arr,
                                kept_pos, kept_key, kept_cnt);
  k_merge<<<4, 1024, 0, stream>>>(cand_box, cand_s, kept_pos, kept_key,
                                  kept_cnt, (float*)d_out);
}

// Round 7
// 221.395 us; speedup vs baseline: 1.2566x; 1.2566x over previous
//
#include <hip/hip_runtime.h>
#include <cstdint>
#include <cstddef>

// ---------------- constants ----------------
__constant__ int LV_N[5]    = {49152, 12288, 3072, 768, 192};   // H*W*3
__constant__ int LV_K[5]    = {2000, 2000, 2000, 768, 192};     // min(PRE_NMS, N)
__constant__ int LV_OFF[5]  = {0, 2000, 4000, 6000, 6768};      // concat offsets
__constant__ int LV_UOFF[5] = {0, 49152, 61440, 64512, 65280};  // u-array offsets
__constant__ int LV_W[5]    = {128, 64, 32, 16, 8};
__constant__ int LV_S[5]    = {4, 8, 16, 32, 64};
__constant__ int LV_LOGHW[5]= {14, 12, 10, 8, 6};
// mask geometry (rows padded by 128 so the scan prefetch never needs bounds tests)
__constant__ int WPL[5]     = {32, 32, 32, 12, 3};              // words per row
__constant__ int MOFF[5]    = {0, 68096, 136192, 204288, 215040};
__constant__ int MB_BASE[6] = {0, 256, 512, 768, 804, 807};     // mask-block bases
__constant__ int MB_CT[5]   = {8, 8, 8, 3, 1};                  // col tiles per lvl
__constant__ int SGB6[6]    = {0, 12, 15, 16, 17, 18};          // 4096-elem tile bases

#define M_TOT 6960
#define U_PER_IMG 65472
#define MAX_OUT 1000
#define MWORDS_PER_IMG 216000
#define CAP 4096

struct Ptrs { const float* cls[5]; const float* reg[5]; };

// ---------------- XLA:CPU-compatible expf (Cephes/Eigen pexp, FMA-contracted) ----
__device__ __forceinline__ float xla_expf(float x) {
  const float exp_hi = 88.3762626647950f;
  const float exp_lo = -88.3762626647949f;
  const float log2ef = 1.44269504088896341f;
  const float c1 = 0.693359375f;
  const float c2 = -2.12194440e-4f;
  const float p0 = 1.9875691500e-4f;
  const float p1 = 1.3981999507e-3f;
  const float p2 = 8.3334519073e-3f;
  const float p3 = 4.1665795894e-2f;
  const float p4 = 1.6666665459e-1f;
  const float p5 = 5.0000001201e-1f;
  float xx = fminf(fmaxf(x, exp_lo), exp_hi);
  float fx = floorf(__fmaf_rn(xx, log2ef, 0.5f));
  float r = __fmaf_rn(fx, -c1, xx);
  r = __fmaf_rn(fx, -c2, r);
  float z = __fmul_rn(r, r);
  float y = __fmaf_rn(p0, r, p1);
  y = __fmaf_rn(y, r, p2);
  y = __fmaf_rn(y, r, p3);
  y = __fmaf_rn(y, r, p4);
  y = __fmaf_rn(y, r, p5);
  y = __fmaf_rn(y, z, r);
  y = __fadd_rn(y, 1.0f);
  int n = (int)fx;
  float two_n = __uint_as_float((unsigned)(n + 127) << 23);
  return __fmul_rn(y, two_n);
}

__device__ __forceinline__ float ref_sigmoid(float x) {
  return __fdiv_rn(1.0f, __fadd_rn(1.0f, xla_expf(-x)));
}

// ================= K0: wide sigmoid + 4096-bin score-bit histogram ============
__global__ __launch_bounds__(1024) void k_sig(Ptrs p, unsigned* u_arr,
                                              unsigned* ghist) {
  const int img = blockIdx.y;
  const int bx = blockIdx.x;
  int lvl = 0;
  while (bx >= SGB6[lvl + 1]) ++lvl;
  const int N = LV_N[lvl], LOGHW = LV_LOGHW[lvl];
  const int HW = 1 << LOGHW;
  const int e0 = (bx - SGB6[lvl]) * 4096;
  const int e1 = (e0 + 4096 < N) ? e0 + 4096 : N;
  const int tid = (int)threadIdx.x;
  __shared__ unsigned h[4096];
  for (int e = tid; e < 4096; e += 1024) h[e] = 0;
  __syncthreads();
  const float* cls = p.cls[lvl] + (size_t)img * N;
  unsigned* u = u_arr + img * U_PER_IMG + LV_UOFF[lvl];
  for (int e = e0 + tid; e < e1; e += 1024) {
    float logit = cls[e];                  // plane-major: fully coalesced
    unsigned ub = __float_as_uint(ref_sigmoid(logit));
    int a = e >> LOGHW, pix = e & (HW - 1);
    u[pix * 3 + a] = ub;                   // channel-last (reference order)
    atomicAdd(&h[(ub >> 18) & 4095u], 1u);
  }
  __syncthreads();
  unsigned* gh = ghist + (size_t)(img * 5 + lvl) * 4096;
  for (int e = tid; e < 4096; e += 1024)
    if (h[e]) atomicAdd(&gh[e], h[e]);
}

// ================= K1a: threshold pick (O(bins), N-scan only on fallback) =====
__global__ __launch_bounds__(1024) void k_thresh(const unsigned* u_arr,
    const unsigned* ghist, unsigned long long* T64_arr) {
  const int blk = blockIdx.x;
  const int img = blk / 5, lvl = blk % 5;
  const int N = LV_N[lvl], K = LV_K[lvl];
  const int tid = (int)threadIdx.x;
  if (N <= K) { if (tid == 0) T64_arr[blk] = 0ULL; return; }
  __shared__ unsigned h[4096], sA[4096], sB[4096];
  __shared__ unsigned sh_D, sh_sD, sh_sD1;
  const unsigned* u = u_arr + img * U_PER_IMG + LV_UOFF[lvl];

  for (int e = tid; e < 4096; e += 1024)
    h[e] = ghist[(size_t)blk * 4096 + e];
  __syncthreads();

  unsigned long long prefix = 0;
  unsigned want = (unsigned)K, above = 0;
  const int shifts[6] = {50, 38, 26, 14, 2, 0};
  const int widths[6] = {12, 12, 12, 12, 12, 2};
  for (int rd = 0; rd < 6; ++rd) {
    const int shift = shifts[rd], width = widths[rd];
    const int nb = 1 << width;
    if (rd > 0) {                          // fallback: exact rescan (rare)
      for (int e = tid; e < nb; e += 1024) h[e] = 0;
      __syncthreads();
      for (int i = tid; i < N; i += 1024) {
        unsigned long long key =
            ((unsigned long long)u[i] << 32) | (unsigned)(~(unsigned)i);
        if ((key >> (shift + width)) == prefix)
          atomicAdd(&h[(unsigned)(key >> shift) & (unsigned)(nb - 1)], 1u);
      }
      __syncthreads();
    }
    // suffix scan s[d] = sum_{v>=d} h[v]
    unsigned *Ap = sA, *Bp = sB;
    for (int e = tid; e < nb; e += 1024) Ap[e] = h[e];
    __syncthreads();
    for (int off = 1; off < nb; off <<= 1) {
      for (int e = tid; e < nb; e += 1024)
        Bp[e] = Ap[e] + ((e + off < nb) ? Ap[e + off] : 0u);
      __syncthreads();
      unsigned* t = Ap; Ap = Bp; Bp = t;
    }
    for (int e = tid; e < nb; e += 1024) {
      unsigned s = Ap[e], sn = (e + 1 < nb) ? Ap[e + 1] : 0u;
      if (s >= want && sn < want) { sh_D = (unsigned)e; sh_sD = s; sh_sD1 = sn; }
    }
    __syncthreads();
    unsigned D = sh_D, sD = sh_sD, sD1 = sh_sD1;
    unsigned long long npref = (prefix << width) | (unsigned long long)D;
    if (above + sD <= (unsigned)CAP || rd == 5) {
      if (tid == 0) T64_arr[blk] = npref << shift;
      return;                              // uniform decision across block
    }
    above += sD1; want -= sD1; prefix = npref;
    __syncthreads();
  }
}

// ================= K1b: wide collect of keys >= T64 (unordered) ==============
__global__ __launch_bounds__(1024) void k_collect(const unsigned* u_arr,
    const unsigned long long* T64_arr, unsigned long long* gtk, unsigned* gcnt) {
  const int img = blockIdx.y;
  const int bx = blockIdx.x;
  int lvl = 0;
  while (bx >= SGB6[lvl + 1]) ++lvl;
  const int N = LV_N[lvl];
  const int e0 = (bx - SGB6[lvl]) * 4096;
  const int e1 = (e0 + 4096 < N) ? e0 + 4096 : N;
  const int tid = (int)threadIdx.x;
  const int lane = tid & 63;
  const unsigned long long T = T64_arr[img * 5 + lvl];
  const unsigned* u = u_arr + img * U_PER_IMG + LV_UOFF[lvl];
  unsigned long long* dst = gtk + (size_t)(img * 5 + lvl) * CAP;
  unsigned* cnt = gcnt + (img * 5 + lvl);
  for (int e = e0 + tid; e < e1; e += 1024) {
    unsigned long long key =
        ((unsigned long long)u[e] << 32) | (unsigned)(~(unsigned)e);
    bool pred = key >= T;
    unsigned long long bm = __ballot(pred);
    if (bm) {
      int leader = __ffsll((long long)bm) - 1;
      unsigned sbase = 0;
      if (lane == leader) sbase = atomicAdd(cnt, (unsigned)__popcll(bm));
      sbase = __shfl(sbase, leader);
      if (pred) {
        unsigned slot = sbase + (unsigned)__popcll(bm & ((1ULL << lane) - 1ULL));
        if (slot < (unsigned)CAP) dst[slot] = key;
      }
    }
  }
}

// ================= K1c: sort P (adaptive) + decode + partition ================
__global__ __launch_bounds__(1024) void k_sort(Ptrs p,
    const unsigned long long* gtk, const unsigned* gcnt,
    float* cand_box, float* cand_s,
    float* n_x1, float* n_y1, float* n_x2, float* n_y2, float* n_ar,
    float* n_sc, unsigned* n_pos, unsigned* V_arr) {
  const int blk = blockIdx.x;
  const int img = blk / 5, lvl = blk % 5;
  const int N = LV_N[lvl], K = LV_K[lvl], W = LV_W[lvl], S = LV_S[lvl];
  const int HW = N / 3;
  const float* reg = p.reg[lvl] + (size_t)img * 12 * HW;
  const int tid = (int)threadIdx.x;

  __shared__ unsigned long long tk[CAP];
  __shared__ unsigned scanA[2048];
  __shared__ unsigned scanB[2048];

  unsigned cnt = gcnt[img * 5 + lvl];
  if (cnt > (unsigned)CAP) cnt = CAP;
  int P = 256;
  while (P < (int)cnt) P <<= 1;            // cnt >= K always, so P >= K
  const unsigned long long* src = gtk + (size_t)(img * 5 + lvl) * CAP;
  for (int e = tid; e < P; e += 1024)
    tk[e] = (e < (int)cnt) ? ~src[e] : ~0ULL;   // flipped -> ascending = score desc

  // bitonic sort P
  for (int size = 2; size < P; size <<= 1) {
    for (int stride = size >> 1; stride > 0; stride >>= 1) {
      __syncthreads();
      for (int q = tid; q < (P >> 1); q += 1024) {
        int pos = 2 * q - (q & (stride - 1));
        bool ddd = ((q & (size >> 1)) == 0);
        unsigned long long A = tk[pos], B = tk[pos + stride];
        if ((A > B) == ddd) { tk[pos] = B; tk[pos + stride] = A; }
      }
    }
  }
  for (int stride = P >> 1; stride > 0; stride >>= 1) {
    __syncthreads();
    for (int q = tid; q < (P >> 1); q += 1024) {
      int pos = 2 * q - (q & (stride - 1));
      unsigned long long A = tk[pos], B = tk[pos + stride];
      if (A > B) { tk[pos] = B; tk[pos + stride] = A; }
    }
  }
  __syncthreads();

  // decode per rank, keep boxes in registers (2 ranks/thread)
  for (int r = tid; r < 2048; r += 1024) scanA[r] = 0u;
  const int KK = K;
  const float MRf = 4.135166556742356f;  // |log(16/1000)| rounded to f32
  float bx1[2], by1[2], bx2[2], by2[2], bsc[2];
  #pragma unroll
  for (int slot = 0; slot < 2; ++slot) {
    int r = tid + slot * 1024;
    if (r >= KK) continue;
    unsigned long long key = ~tk[r];
    unsigned ubits = (unsigned)(key >> 32);
    unsigned idx = ~((unsigned)key);
    int a = (int)(idx % 3u); int pix = (int)(idx / 3u);
    int xq = pix % W, yq = pix / W;
    float dx = reg[(a * 4 + 0) * HW + pix];
    float dy = reg[(a * 4 + 1) * HW + pix];
    float dw = reg[(a * 4 + 2) * HW + pix];
    float dh = reg[(a * 4 + 3) * HW + pix];
    double rr = (a == 0) ? 0.5 : (a == 1 ? 1.0 : 2.0);
    double hr = sqrt(rr), wr = 1.0 / hr;
    double st = (double)S;
    double wsd = st * wr * 8.0, hsd = st * hr * 8.0;
    double sxd = (double)(xq * S), syd = (double)(yq * S);
    float a0 = (float)(sxd - 0.5 * wsd), a1 = (float)(syd - 0.5 * hsd);
    float a2 = (float)(sxd + 0.5 * wsd), a3 = (float)(syd + 0.5 * hsd);
    float px = __fmul_rn(__fadd_rn(a0, a2), 0.5f);
    float py = __fmul_rn(__fadd_rn(a1, a3), 0.5f);
    float pw = __fsub_rn(a2, a0), ph = __fsub_rn(a3, a1);
    float dwc = fminf(fmaxf(dw, -MRf), MRf);
    float dhc = fminf(fmaxf(dh, -MRf), MRf);
    float gw = __fmul_rn(pw, xla_expf(dwc));
    float gh = __fmul_rn(ph, xla_expf(dhc));
    float gx = __fmaf_rn(pw, dx, px);
    float gy = __fmaf_rn(ph, dy, py);
    float x1 = fminf(fmaxf(__fmaf_rn(gw, -0.5f, gx), 0.0f), 512.0f);
    float y1 = fminf(fmaxf(__fmaf_rn(gh, -0.5f, gy), 0.0f), 512.0f);
    float x2 = fminf(fmaxf(__fmaf_rn(gw,  0.5f, gx), 0.0f), 512.0f);
    float y2 = fminf(fmaxf(__fmaf_rn(gh,  0.5f, gy), 0.0f), 512.0f);
    bool valid = (__fsub_rn(x2, x1) > 0.0f) && (__fsub_rn(y2, y1) > 0.0f);
    int pos = img * M_TOT + LV_OFF[lvl] + r;
    cand_box[(size_t)pos * 4 + 0] = x1;
    cand_box[(size_t)pos * 4 + 1] = y1;
    cand_box[(size_t)pos * 4 + 2] = x2;
    cand_box[(size_t)pos * 4 + 3] = y2;
    float score = __uint_as_float(ubits);
    float sc = valid ? score : -1.0f;
    cand_s[pos] = sc;
    scanA[r] = valid ? 1u : 0u;
    bx1[slot] = x1; by1[slot] = y1; bx2[slot] = x2; by2[slot] = y2;
    bsc[slot] = sc;
  }
  __syncthreads();

  // stable partition (valids first) via inclusive scan over 2048
  unsigned* Ap = scanA; unsigned* Bp = scanB;
  for (int off = 1; off < 2048; off <<= 1) {
    for (int r2 = tid; r2 < 2048; r2 += 1024)
      Bp[r2] = Ap[r2] + ((r2 >= off) ? Ap[r2 - off] : 0u);
    __syncthreads();
    unsigned* t = Ap; Ap = Bp; Bp = t;
  }
  unsigned V = (KK > 0) ? Ap[KK - 1] : 0u;
  const float offv = __fmul_rn((float)lvl, 513.0f);
  #pragma unroll
  for (int slot = 0; slot < 2; ++slot) {
    int r = tid + slot * 1024;
    if (r >= KK) continue;
    unsigned incl = Ap[r];
    unsigned fl = incl - ((r > 0) ? Ap[r - 1] : 0u);
    unsigned excl = incl - fl;
    unsigned pdst = fl ? excl : V + ((unsigned)r - excl);
    int dst = img * M_TOT + LV_OFF[lvl] + (int)pdst;
    float ox1 = __fadd_rn(bx1[slot], offv), oy1 = __fadd_rn(by1[slot], offv);
    float ox2 = __fadd_rn(bx2[slot], offv), oy2 = __fadd_rn(by2[slot], offv);
    n_x1[dst] = ox1; n_y1[dst] = oy1; n_x2[dst] = ox2; n_y2[dst] = oy2;
    n_ar[dst] = __fmul_rn(__fsub_rn(ox2, ox1), __fsub_rn(oy2, oy1));
    n_sc[dst] = bsc[slot];
    n_pos[dst] = (unsigned)(LV_OFF[lvl] + r);
  }
  if (tid == 0) V_arr[img * 5 + lvl] = V;
}

// ================= K2a: suppression bit-matrix build =========================
__global__ __launch_bounds__(256) void k_mask(
    const float* n_x1, const float* n_y1, const float* n_x2, const float* n_y2,
    const float* n_ar, unsigned long long* mask) {
  const int img = blockIdx.y;
  const int bx = blockIdx.x;
  int lvl = 0;
  while (bx >= MB_BASE[lvl + 1]) ++lvl;
  const int t = bx - MB_BASE[lvl];
  const int ct = MB_CT[lvl];
  const int rt = t / ct, c = t % ct;
  const int K = LV_K[lvl];
  const int row0 = rt * 64, col0 = c * 256;
  if (col0 + 255 <= row0) return;  // entire tile has j <= r: bits never consumed

  __shared__ float4 cb4[256];
  __shared__ float cba[256];
  __shared__ float4 rb4[64];
  __shared__ float rba[64];
  const int base = img * M_TOT + LV_OFF[lvl];
  const int tid = (int)threadIdx.x;
  if (tid < 64) {
    int r = row0 + tid;
    if (r < K) {
      rb4[tid] = make_float4(n_x1[base + r], n_y1[base + r],
                             n_x2[base + r], n_y2[base + r]);
      rba[tid] = n_ar[base + r];
    }
  }
  {
    int j = col0 + tid;
    if (j < K) {
      cb4[tid] = make_float4(n_x1[base + j], n_y1[base + j],
                             n_x2[base + j], n_y2[base + j]);
      cba[tid] = n_ar[base + j];
    }
  }
  __syncthreads();
  const int wl = tid >> 6, rl = tid & 63;
  const int r = row0 + rl;
  if (r >= K) return;
  const float4 rb = rb4[rl];
  const float rar = rba[rl];
  unsigned long long word = 0ULL;
  const int jbase = wl * 64;
  const int jmax = K - col0 - jbase;   // bit k valid iff k < jmax
  #pragma unroll 16
  for (int k = 0; k < 64; ++k) {
    float4 cb = cb4[jbase + k];        // broadcast: all lanes same address
    float car = cba[jbase + k];
    float iw = fmaxf(__fsub_rn(fminf(rb.z, cb.z), fmaxf(rb.x, cb.x)), 0.0f);
    float ih = fmaxf(__fsub_rn(fminf(rb.w, cb.w), fmaxf(rb.y, cb.y)), 0.0f);
    float inter = __fmul_rn(iw, ih);
    float uni = __fsub_rn(__fadd_rn(rar, car), inter);
    float iou = (uni > 0.0f) ? __fdiv_rn(inter, uni) : 0.0f;
    if (iou > 0.7f && k < jmax) word |= (1ULL << k);
  }
  mask[(size_t)img * MWORDS_PER_IMG + MOFF[lvl] +
       (size_t)r * WPL[lvl] + (size_t)((col0 >> 6) + wl)] = word;
}

// ================= K2b: chunked greedy scan (64 rows at a time) ===============
// Lane i holds the diag-block word of row r0+i; 6-stage shfl_xor bit-transpose
// gives lane j its suppressor COLUMN. In-chunk greedy = ballot fixpoint
// (provably = exact greedy, converges in <= #candidates-in-chunk rounds).
// Cross-chunk: branchless alive &= ~(rowb[d] & sext(kw bit d)), rowb ring
// refilled one full chunk ahead.
#define TSTAGE(S, M)                                                        \
  {                                                                         \
    unsigned long long t_ = __shfl_xor(x, S);                               \
    x = (lane & S) ? ((x & (M)) | ((t_ >> S) & ~(M)))                       \
                   : ((x & ~(M)) | ((t_ << S) & (M)));                      \
  }

__global__ __launch_bounds__(64) void k_scan(const unsigned long long* mask,
    const unsigned* n_pos, const float* n_sc, const unsigned* V_arr,
    unsigned* kept_pos, unsigned long long* kept_key, unsigned* kept_cnt) {
  const int blk = blockIdx.x;
  const int img = blk / 5, lvl = blk % 5;
  const int K = LV_K[lvl], wpl = WPL[lvl];
  const int lane = (int)threadIdx.x;
  const unsigned long long* mb =
      mask + (size_t)img * MWORDS_PER_IMG + MOFF[lvl];
  const int ln = lane < wpl ? lane : 0;  // clamped word index (dup loads ok)

  __shared__ unsigned skept[MAX_OUT + 64];

  const int V = (int)V_arr[img * 5 + lvl];
  unsigned long long alive = 0ULL;
  if (lane < wpl) {
    int lo = lane * 64, hi = V < lo + 64 ? V : lo + 64;
    if (hi > lo) alive = (hi - lo == 64) ? ~0ULL : ((1ULL << (hi - lo)) - 1ULL);
  }
  const unsigned long long below = (1ULL << lane) - 1ULL;

  unsigned long long rowb[64];
  #pragma unroll
  for (int d = 0; d < 64; ++d) rowb[d] = mb[(size_t)d * wpl + ln];
  unsigned long long dnext = mb[(size_t)lane * wpl];  // chunk 0 diag (word 0)

  int kept = 0;
  const int nchunks = (K + 63) >> 6;
  for (int c = 0; c < nchunks; ++c) {
    const int r0 = c << 6;
    // transpose: lane j <- column j of the 64x64 diag block
    unsigned long long x = dnext;
    TSTAGE(32, 0xFFFFFFFF00000000ULL)
    TSTAGE(16, 0xFFFF0000FFFF0000ULL)
    TSTAGE(8,  0xFF00FF00FF00FF00ULL)
    TSTAGE(4,  0xF0F0F0F0F0F0F0F0ULL)
    TSTAGE(2,  0xCCCCCCCCCCCCCCCCULL)
    TSTAGE(1,  0xAAAAAAAAAAAAAAAAULL)
    // issue next chunk's diag load (padded region -> always in-bounds)
    dnext = mb[(size_t)(r0 + 64 + lane) * wpl + (c + 1)];

    // in-chunk greedy fixpoint
    unsigned long long aw = __shfl(alive, c);
    unsigned long long kw = aw;
    while (true) {
      bool keep_j = (((aw >> lane) & 1ULL) != 0ULL) &&
                    ((kw & below & x) == 0ULL);
      unsigned long long nkw = __ballot(keep_j);
      if (nkw == kw) break;
      kw = nkw;
    }

    // record kept rows (parallel popcount-prefix)
    if ((kw >> lane) & 1ULL) {
      int idx = kept + (int)__popcll(kw & below);
      skept[idx] = (unsigned)(r0 + lane);
    }
    kept += (int)__popcll(kw);

    // cross-chunk suppression (branchless) + rowb refill one chunk ahead
    #pragma unroll
    for (int d = 0; d < 64; ++d) {
      unsigned long long m =
          (unsigned long long)((long long)(kw << (63 - d)) >> 63);
      alive &= ~(rowb[d] & m);
      rowb[d] = mb[(size_t)(r0 + 64 + d) * wpl + ln];
    }
    if (kept >= MAX_OUT) break;   // overshoot <=64 buffered; truncated below
  }
  if (kept > MAX_OUT) kept = MAX_OUT;
  __syncthreads();
  const int base = img * M_TOT + LV_OFF[lvl];
  const size_t bo = (size_t)(img * 5 + lvl) * 1024;
  for (int i = lane; i < kept; i += 64) {
    unsigned r = skept[i];
    unsigned pp = n_pos[base + (int)r];
    kept_pos[bo + i] = pp;
    kept_key[bo + i] =
        ((unsigned long long)__float_as_uint(n_sc[base + (int)r]) << 32) |
        (unsigned)(~pp);
  }
  if (lane == 0) kept_cnt[img * 5 + lvl] = (unsigned)kept;
}

// ================= K3: per-image merge of kept lists -> output rows ===========
__global__ __launch_bounds__(1024) void k_merge(const float* cand_box,
    const float* cand_s, const unsigned* kept_pos,
    const unsigned long long* kept_key, const unsigned* kept_cnt, float* out) {
  const int img = blockIdx.x;
  const int tid = (int)threadIdx.x;
  __shared__ unsigned cnts[5];
  __shared__ unsigned long long skey[5][1024];
  if (tid < 5) {
    unsigned c = kept_cnt[img * 5 + tid];
    cnts[tid] = c < (unsigned)MAX_OUT ? c : (unsigned)MAX_OUT;
  }
  __syncthreads();
  for (int e = tid; e < 5 * 1024; e += 1024) {
    int l = e >> 10, s = e & 1023;
    skey[l][s] = (s < (int)cnts[l])
        ? kept_key[(size_t)(img * 5 + l) * 1024 + s] : 0ULL;
  }
  __syncthreads();
  unsigned T = cnts[0] + cnts[1] + cnts[2] + cnts[3] + cnts[4];
  unsigned Tc = T < (unsigned)MAX_OUT ? T : (unsigned)MAX_OUT;
  for (int r = (int)Tc + tid; r < MAX_OUT; r += 1024) {
    float* o = out + (size_t)img * (MAX_OUT * 5) + (size_t)r * 5;
    o[0] = 0.f; o[1] = 0.f; o[2] = 0.f; o[3] = 0.f; o[4] = 0.f;
  }
  for (int e = tid; e < 5 * 1024; e += 1024) {
    int l = e >> 10, s = e & 1023;
    if (s >= (int)cnts[l]) continue;
    unsigned long long k0 = skey[l][s];
    unsigned rank = (unsigned)s;
    #pragma unroll
    for (int l2 = 0; l2 < 5; ++l2) {
      if (l2 == l) continue;
      int lo = 0, hi = (int)cnts[l2];
      while (lo < hi) {
        int mid = (lo + hi) >> 1;
        if (skey[l2][mid] > k0) lo = mid + 1; else hi = mid;
      }
      rank += (unsigned)lo;
    }
    if (rank < (unsigned)MAX_OUT) {
      unsigned pos = kept_pos[(size_t)(img * 5 + l) * 1024 + s];
      const float* b = cand_box + (size_t)(img * M_TOT + pos) * 4;
      float* o = out + (size_t)img * (MAX_OUT * 5) + (size_t)rank * 5;
      o[0] = b[0]; o[1] = b[1]; o[2] = b[2]; o[3] = b[3];
      o[4] = cand_s[img * M_TOT + pos];
    }
  }
}

// ================= host launch =================
extern "C" void kernel_launch(void* const* d_in, const int* in_sizes, int n_in,
                              void* d_out, int out_size, void* d_ws, size_t ws_size,
                              hipStream_t stream) {
  Ptrs p;
  bool interleaved = (n_in == 10 && in_sizes[1] == 4 * 12 * 128 * 128);
  for (int l = 0; l < 5; ++l) {
    if (interleaved) {
      p.cls[l] = (const float*)d_in[2 * l];
      p.reg[l] = (const float*)d_in[2 * l + 1];
    } else {
      p.cls[l] = (const float*)d_in[l];
      p.reg[l] = (const float*)d_in[5 + l];
    }
  }
  uint8_t* w = (uint8_t*)d_ws;
  size_t o = 0;
  auto carve = [&](size_t bytes) {
    void* ptr = w + o;
    o += (bytes + 255) & ~(size_t)255;
    return ptr;
  };
  // gcnt + ghist adjacent -> one memset zeroes both
  unsigned* gcnt = (unsigned*)carve((size_t)20 * 4);                 // 256B slot
  unsigned* ghist = (unsigned*)carve((size_t)20 * 4096 * 4);
  size_t zero_bytes = 256 + (size_t)20 * 4096 * 4;
  unsigned long long* T64_arr = (unsigned long long*)carve((size_t)20 * 8);
  unsigned* u_arr = (unsigned*)carve((size_t)4 * U_PER_IMG * 4);
  float* cand_box = (float*)carve((size_t)4 * M_TOT * 4 * 4);
  float* cand_s = (float*)carve((size_t)4 * M_TOT * 4);
  float* n_x1 = (float*)carve((size_t)4 * M_TOT * 4);
  float* n_y1 = (float*)carve((size_t)4 * M_TOT * 4);
  float* n_x2 = (float*)carve((size_t)4 * M_TOT * 4);
  float* n_y2 = (float*)carve((size_t)4 * M_TOT * 4);
  float* n_ar = (float*)carve((size_t)4 * M_TOT * 4);
  float* n_sc = (float*)carve((size_t)4 * M_TOT * 4);
  unsigned* n_pos = (unsigned*)carve((size_t)4 * M_TOT * 4);
  unsigned* V_arr = (unsigned*)carve((size_t)20 * 4);
  unsigned* kept_pos = (unsigned*)carve((size_t)4 * 5 * 1024 * 4);
  unsigned long long* kept_key = (unsigned long long*)carve((size_t)4 * 5 * 1024 * 8);
  unsigned* kept_cnt = (unsigned*)carve((size_t)20 * 4);
  unsigned long long* mask = (unsigned long long*)carve((size_t)4 * MWORDS_PER_IMG * 8);
  // gtk (20*4096 u64 = 640KB) aliases mask: dead before k_mask writes it.
  unsigned long long* gtk = mask;
  (void)ws_size; (void)out_size;

  hipMemsetAsync(gcnt, 0, zero_bytes, stream);
  k_sig<<<dim3(18, 4), 1024, 0, stream>>>(p, u_arr, ghist);
  k_thresh<<<20, 1024, 0, stream>>>(u_arr, ghist, T64_arr);
  k_collect<<<dim3(18, 4), 1024, 0, stream>>>(u_arr, T64_arr, gtk, gcnt);
  k_sort<<<20, 1024, 0, stream>>>(p, gtk, gcnt, cand_box, cand_s,
      n_x1, n_y1, n_x2, n_y2, n_ar, n_sc, n_pos, V_arr);
  k_mask<<<dim3(807, 4), 256, 0, stream>>>(n_x1, n_y1, n_x2, n_y2, n_ar, mask);
  k_scan<<<20, 64, 0, stream>>>(mask, n_pos, n_sc, V_arr,
                                kept_pos, kept_key, kept_cnt);
  k_merge<<<4, 1024, 0, stream>>>(cand_box, cand_s, kept_pos, kept_key,
                                  kept_cnt, (float*)d_out);
}